// Round 1
// baseline (2290.698 us; speedup 1.0000x reference)
//
#include <hip/hip_runtime.h>

// ---------------------------------------------------------------------------
// 3-layer GCN: h = relu(GCNConv(...)) x3
// agg[n] = sum_{e: dst=n} hw[src_e]*norm_e + hw[n]*dis[n]^2 + b
// norm_e = dis[src]*dis[dst], dis = rsqrt(indeg+1)
// ---------------------------------------------------------------------------

__global__ __launch_bounds__(256) void k_deg(const int* __restrict__ dst,
                                             float* __restrict__ deg, int nE) {
    int e = blockIdx.x * 256 + threadIdx.x;
    if (e < nE) atomicAdd(&deg[dst[e]], 1.0f);
}

__global__ __launch_bounds__(256) void k_rsqrt(float* deg, int nN) {
    int i = blockIdx.x * 256 + threadIdx.x;
    if (i < nN) deg[i] = rsqrtf(deg[i] + 1.0f);
}

__global__ __launch_bounds__(256) void k_norm(const int* __restrict__ src,
                                              const int* __restrict__ dst,
                                              const float* __restrict__ dis,
                                              float* __restrict__ norm, int nE) {
    int e = blockIdx.x * 256 + threadIdx.x;
    if (e < nE) norm[e] = dis[src[e]] * dis[dst[e]];
}

// Y = (relu?(X)) @ W   [nrows x 128] @ [128 x 128]
// HW  <- Y
// AGG <- Y * dis[row]^2 + bias      (self-loop + bias folded into agg init)
// NOTE: X and AGG may alias (in-place): each block reads ONLY its own 64 rows,
// fully staged into LDS before any global store. No __restrict__ on X/AGG.
__global__ __launch_bounds__(256) void k_gemm128(const float* X,
                                                 const float* __restrict__ W,
                                                 const float* __restrict__ dis,
                                                 const float* __restrict__ bias,
                                                 float* __restrict__ HW,
                                                 float* AGG,
                                                 int nrows, int relu_in) {
    __shared__ float xs[64 * 128];   // 32 KB: X tile [64 rows][128 k]
    __shared__ float wsm[32 * 128];  // 16 KB: W chunk [32 k][128 cols]
    const int t = threadIdx.x;
    const int row0 = blockIdx.x * 64;
    const int tr = t >> 5;   // 0..7  -> 8 rows each
    const int tc = t & 31;   // 0..31 -> 4 cols each

    float acc[8][4];
#pragma unroll
    for (int i = 0; i < 8; ++i)
#pragma unroll
        for (int c = 0; c < 4; ++c) acc[i][c] = 0.f;

    // stage X tile: 2048 float4, 8 per thread, coalesced
#pragma unroll
    for (int i = 0; i < 8; ++i) {
        int f = t + i * 256;          // float4 index in tile
        int r = f >> 5, k4 = f & 31;
        int gr = row0 + r;
        float4 v = make_float4(0.f, 0.f, 0.f, 0.f);
        if (gr < nrows) v = ((const float4*)X)[(size_t)gr * 32 + k4];
        if (relu_in) {
            v.x = fmaxf(v.x, 0.f); v.y = fmaxf(v.y, 0.f);
            v.z = fmaxf(v.z, 0.f); v.w = fmaxf(v.w, 0.f);
        }
        ((float4*)xs)[f] = v;
    }

    for (int kk = 0; kk < 128; kk += 32) {
        // stage W rows kk..kk+31 (1024 float4, 4 per thread)
#pragma unroll
        for (int i = 0; i < 4; ++i) {
            int f = t + i * 256;
            ((float4*)wsm)[f] = ((const float4*)W)[kk * 32 + f];
        }
        __syncthreads();
#pragma unroll
        for (int k4 = 0; k4 < 8; ++k4) {
            float4 b0 = *(const float4*)&wsm[(k4 * 4 + 0) * 128 + tc * 4];
            float4 b1 = *(const float4*)&wsm[(k4 * 4 + 1) * 128 + tc * 4];
            float4 b2 = *(const float4*)&wsm[(k4 * 4 + 2) * 128 + tc * 4];
            float4 b3 = *(const float4*)&wsm[(k4 * 4 + 3) * 128 + tc * 4];
#pragma unroll
            for (int i = 0; i < 8; ++i) {
                float4 a = *(const float4*)&xs[(tr * 8 + i) * 128 + kk + k4 * 4];
                acc[i][0] += a.x * b0.x + a.y * b1.x + a.z * b2.x + a.w * b3.x;
                acc[i][1] += a.x * b0.y + a.y * b1.y + a.z * b2.y + a.w * b3.y;
                acc[i][2] += a.x * b0.z + a.y * b1.z + a.z * b2.z + a.w * b3.z;
                acc[i][3] += a.x * b0.w + a.y * b1.w + a.z * b2.w + a.w * b3.w;
            }
        }
        __syncthreads();  // compute done before next W staging / epilogue
    }

    const float4 bv = ((const float4*)bias)[tc];
#pragma unroll
    for (int i = 0; i < 8; ++i) {
        int gr = row0 + tr * 8 + i;
        if (gr < nrows) {
            float dn = dis[gr];
            float sn = dn * dn;
            float4 hv = make_float4(acc[i][0], acc[i][1], acc[i][2], acc[i][3]);
            ((float4*)HW)[(size_t)gr * 32 + tc] = hv;
            float4 av = make_float4(hv.x * sn + bv.x, hv.y * sn + bv.y,
                                    hv.z * sn + bv.z, hv.w * sn + bv.w);
            ((float4*)AGG)[(size_t)gr * 32 + tc] = av;
        }
    }
}

// per edge: agg[dst] += hw[src] * norm_e   (32 threads/edge, float4 gather)
__global__ __launch_bounds__(256) void k_scatter(const float* __restrict__ HW,
                                                 const int* __restrict__ src,
                                                 const int* __restrict__ dst,
                                                 const float* __restrict__ norm,
                                                 float* __restrict__ AGG, int nE) {
    int tid = blockIdx.x * 256 + threadIdx.x;
    int e = tid >> 5;
    if (e >= nE) return;
    int f4 = tid & 31;
    int s = src[e], d = dst[e];
    float nv = norm[e];
    float4 v = ((const float4*)HW)[(size_t)s * 32 + f4];
    float* out = &AGG[(size_t)d * 128 + f4 * 4];
    atomicAdd(out + 0, v.x * nv);
    atomicAdd(out + 1, v.y * nv);
    atomicAdd(out + 2, v.z * nv);
    atomicAdd(out + 3, v.w * nv);
}

// layer 3: hw3[n] = dot(relu(h2[n,:]), W3);  agg3[n] = hw3[n]*dis^2 + b3
__global__ __launch_bounds__(256) void k_gemv(const float* __restrict__ H,
                                              const float* __restrict__ W3,
                                              const float* __restrict__ b3,
                                              const float* __restrict__ dis,
                                              float* __restrict__ hw3,
                                              float* __restrict__ agg3, int nN) {
    int wid = (blockIdx.x * 256 + threadIdx.x) >> 6;  // one wave per node
    int lane = threadIdx.x & 63;
    if (wid >= nN) return;
    float v0 = fmaxf(H[(size_t)wid * 128 + lane], 0.f);
    float v1 = fmaxf(H[(size_t)wid * 128 + 64 + lane], 0.f);
    float sum = v0 * W3[lane] + v1 * W3[64 + lane];
#pragma unroll
    for (int off = 32; off > 0; off >>= 1) sum += __shfl_down(sum, off);
    if (lane == 0) {
        hw3[wid] = sum;
        float dn = dis[wid];
        agg3[wid] = sum * dn * dn + b3[0];
    }
}

__global__ __launch_bounds__(256) void k_scatter3(const float* __restrict__ hw3,
                                                  const int* __restrict__ src,
                                                  const int* __restrict__ dst,
                                                  const float* __restrict__ norm,
                                                  float* __restrict__ agg3, int nE) {
    int e = blockIdx.x * 256 + threadIdx.x;
    if (e < nE) atomicAdd(&agg3[dst[e]], hw3[src[e]] * norm[e]);
}

__global__ __launch_bounds__(256) void k_final(const float* __restrict__ agg3,
                                               float* __restrict__ out, int nN) {
    int i = blockIdx.x * 256 + threadIdx.x;
    if (i < nN) out[i] = fmaxf(agg3[i], 0.f);
}

extern "C" void kernel_launch(void* const* d_in, const int* in_sizes, int n_in,
                              void* d_out, int out_size, void* d_ws, size_t ws_size,
                              hipStream_t stream) {
    const float* x  = (const float*)d_in[0];
    const int*   ei = (const int*)d_in[1];
    const float* W1 = (const float*)d_in[2];
    const float* b1 = (const float*)d_in[3];
    const float* W2 = (const float*)d_in[4];
    const float* b2 = (const float*)d_in[5];
    const float* W3 = (const float*)d_in[6];
    const float* b3 = (const float*)d_in[7];

    const int nN = in_sizes[0] / 128;
    const int nE = in_sizes[1] / 2;
    const int* src = ei;
    const int* dst = ei + nE;

    float* ws   = (float*)d_ws;
    float* dis  = ws;                         // nN
    float* norm = dis + nN;                   // nE
    float* bufA = norm + nE;                  // nN*128 (hw, all layers)
    float* bufB = bufA + (size_t)nN * 128;    // nN*128 (agg/h ping buffer)
    float* hw3  = bufB + (size_t)nN * 128;    // nN
    float* agg3 = hw3 + nN;                   // nN

    const int BE   = (nE + 255) / 256;
    const int BN   = (nN + 255) / 256;
    const int BG   = (nN + 63) / 64;
    const int BS   = (nE * 32 + 255) / 256;
    const int BGV  = (nN + 3) / 4;

    // --- norm precompute ---
    hipMemsetAsync(dis, 0, (size_t)nN * sizeof(float), stream);
    k_deg  <<<BE, 256, 0, stream>>>(dst, dis, nE);
    k_rsqrt<<<BN, 256, 0, stream>>>(dis, nN);
    k_norm <<<BE, 256, 0, stream>>>(src, dst, dis, norm, nE);

    // --- layer 1: x -> bufB ---
    k_gemm128<<<BG, 256, 0, stream>>>(x, W1, dis, b1, bufA, bufB, nN, 0);
    k_scatter<<<BS, 256, 0, stream>>>(bufA, src, dst, norm, bufB, nE);

    // --- layer 2: relu(bufB) -> bufB (in-place agg init is safe per-block) ---
    k_gemm128<<<BG, 256, 0, stream>>>(bufB, W2, dis, b2, bufA, bufB, nN, 1);
    k_scatter<<<BS, 256, 0, stream>>>(bufA, src, dst, norm, bufB, nE);

    // --- layer 3: relu(bufB) -> d_out ---
    k_gemv    <<<BGV, 256, 0, stream>>>(bufB, W3, b3, dis, hw3, agg3, nN);
    k_scatter3<<<BE, 256, 0, stream>>>(hw3, src, dst, norm, agg3, nE);
    k_final   <<<BN, 256, 0, stream>>>(agg3, (float*)d_out, nN);
}

// Round 2
// 483.301 us; speedup vs baseline: 4.7397x; 4.7397x over previous
//
#include <hip/hip_runtime.h>

// ---------------------------------------------------------------------------
// 3-layer GCN, CSR-gather formulation (no fp32 atomics in the hot path).
// Per call: build CSR by dst (count -> scan -> bin), then per layer:
//   GEMM (writes hw + agg-init with self-loop & bias folded in)
//   gather: agg[n] += sum_{e in CSR[n]} hw[src_e] * norm_e   (register acc)
// ---------------------------------------------------------------------------

__global__ __launch_bounds__(256) void k_count(const int* __restrict__ dst,
                                               int* __restrict__ cnt, int nE) {
    int e = blockIdx.x * 256 + threadIdx.x;
    if (e < nE) atomicAdd(&cnt[dst[e]], 1);
}

__global__ __launch_bounds__(256) void k_rsqrt(const int* __restrict__ cnt,
                                               float* __restrict__ dis, int nN) {
    int i = blockIdx.x * 256 + threadIdx.x;
    if (i < nN) dis[i] = rsqrtf((float)cnt[i] + 1.0f);
}

// single-block exclusive scan of cnt[0..nN) -> row_ptr; cursor(=cnt, in place)
// also gets the exclusive offsets for the binning pass.
__global__ __launch_bounds__(1024) void k_scan(int* __restrict__ cnt,
                                               int* __restrict__ row_ptr, int nN) {
    __shared__ int sm[1024];
    __shared__ int run_s;
    const int t = threadIdx.x;
    if (t == 0) run_s = 0;
    __syncthreads();
    for (int base = 0; base < nN; base += 1024) {
        int i = base + t;
        int v = (i < nN) ? cnt[i] : 0;
        sm[t] = v;
        __syncthreads();
        for (int off = 1; off < 1024; off <<= 1) {
            int x = (t >= off) ? sm[t - off] : 0;
            __syncthreads();
            sm[t] += x;
            __syncthreads();
        }
        int run = run_s;
        int excl = run + sm[t] - v;
        int total = sm[1023];
        if (i < nN) { row_ptr[i] = excl; cnt[i] = excl; }  // cnt becomes cursor
        __syncthreads();
        if (t == 0) run_s = run + total;
        __syncthreads();
    }
    if (t == 0) row_ptr[nN] = run_s;
}

__global__ __launch_bounds__(256) void k_bin(const int* __restrict__ src,
                                             const int* __restrict__ dst,
                                             const float* __restrict__ dis,
                                             int* __restrict__ cursor,
                                             int* __restrict__ src_csr,
                                             float* __restrict__ norm_csr, int nE) {
    int e = blockIdx.x * 256 + threadIdx.x;
    if (e >= nE) return;
    int s = src[e], d = dst[e];
    int pos = atomicAdd(&cursor[d], 1);
    src_csr[pos] = s;
    norm_csr[pos] = dis[s] * dis[d];
}

// Y = (relu?(X)) @ W   [nrows x 128] @ [128 x 128]
// HW  <- Y ;  AGG <- Y * dis[row]^2 + bias   (self-loop + bias folded in)
// X and AGG may alias: each block stages its own 64 rows to LDS before storing.
__global__ __launch_bounds__(256) void k_gemm128(const float* X,
                                                 const float* __restrict__ W,
                                                 const float* __restrict__ dis,
                                                 const float* __restrict__ bias,
                                                 float* __restrict__ HW,
                                                 float* AGG,
                                                 int nrows, int relu_in) {
    __shared__ float xs[64 * 128];
    __shared__ float wsm[32 * 128];
    const int t = threadIdx.x;
    const int row0 = blockIdx.x * 64;
    const int tr = t >> 5;
    const int tc = t & 31;

    float acc[8][4];
#pragma unroll
    for (int i = 0; i < 8; ++i)
#pragma unroll
        for (int c = 0; c < 4; ++c) acc[i][c] = 0.f;

#pragma unroll
    for (int i = 0; i < 8; ++i) {
        int f = t + i * 256;
        int r = f >> 5, k4 = f & 31;
        int gr = row0 + r;
        float4 v = make_float4(0.f, 0.f, 0.f, 0.f);
        if (gr < nrows) v = ((const float4*)X)[(size_t)gr * 32 + k4];
        if (relu_in) {
            v.x = fmaxf(v.x, 0.f); v.y = fmaxf(v.y, 0.f);
            v.z = fmaxf(v.z, 0.f); v.w = fmaxf(v.w, 0.f);
        }
        ((float4*)xs)[f] = v;
    }

    for (int kk = 0; kk < 128; kk += 32) {
#pragma unroll
        for (int i = 0; i < 4; ++i) {
            int f = t + i * 256;
            ((float4*)wsm)[f] = ((const float4*)W)[kk * 32 + f];
        }
        __syncthreads();
#pragma unroll
        for (int k4 = 0; k4 < 8; ++k4) {
            float4 b0 = *(const float4*)&wsm[(k4 * 4 + 0) * 128 + tc * 4];
            float4 b1 = *(const float4*)&wsm[(k4 * 4 + 1) * 128 + tc * 4];
            float4 b2 = *(const float4*)&wsm[(k4 * 4 + 2) * 128 + tc * 4];
            float4 b3 = *(const float4*)&wsm[(k4 * 4 + 3) * 128 + tc * 4];
#pragma unroll
            for (int i = 0; i < 8; ++i) {
                float4 a = *(const float4*)&xs[(tr * 8 + i) * 128 + kk + k4 * 4];
                acc[i][0] += a.x * b0.x + a.y * b1.x + a.z * b2.x + a.w * b3.x;
                acc[i][1] += a.x * b0.y + a.y * b1.y + a.z * b2.y + a.w * b3.y;
                acc[i][2] += a.x * b0.z + a.y * b1.z + a.z * b2.z + a.w * b3.z;
                acc[i][3] += a.x * b0.w + a.y * b1.w + a.z * b2.w + a.w * b3.w;
            }
        }
        __syncthreads();
    }

    const float4 bv = ((const float4*)bias)[tc];
#pragma unroll
    for (int i = 0; i < 8; ++i) {
        int gr = row0 + tr * 8 + i;
        if (gr < nrows) {
            float dn = dis[gr];
            float sn = dn * dn;
            float4 hv = make_float4(acc[i][0], acc[i][1], acc[i][2], acc[i][3]);
            ((float4*)HW)[(size_t)gr * 32 + tc] = hv;
            float4 av = make_float4(hv.x * sn + bv.x, hv.y * sn + bv.y,
                                    hv.z * sn + bv.z, hv.w * sn + bv.w);
            ((float4*)AGG)[(size_t)gr * 32 + tc] = av;
        }
    }
}

// pull-aggregation: 32 threads per node, float4 per thread, register acc,
// single write per output element. AGG pre-initialized with self-loop + bias.
__global__ __launch_bounds__(256) void k_gather(const float* __restrict__ HW,
                                                const int* __restrict__ row_ptr,
                                                const int* __restrict__ src_csr,
                                                const float* __restrict__ norm_csr,
                                                float* __restrict__ AGG, int nN) {
    int g = blockIdx.x * 8 + (threadIdx.x >> 5);
    if (g >= nN) return;
    int f4 = threadIdx.x & 31;
    int beg = row_ptr[g], end = row_ptr[g + 1];
    float4 acc = ((const float4*)AGG)[(size_t)g * 32 + f4];
    int e = beg;
    for (; e + 1 < end; e += 2) {  // 2-way unroll for load ILP
        int s0 = src_csr[e], s1 = src_csr[e + 1];
        float n0 = norm_csr[e], n1 = norm_csr[e + 1];
        float4 v0 = ((const float4*)HW)[(size_t)s0 * 32 + f4];
        float4 v1 = ((const float4*)HW)[(size_t)s1 * 32 + f4];
        acc.x += v0.x * n0 + v1.x * n1;
        acc.y += v0.y * n0 + v1.y * n1;
        acc.z += v0.z * n0 + v1.z * n1;
        acc.w += v0.w * n0 + v1.w * n1;
    }
    if (e < end) {
        int s = src_csr[e];
        float nv = norm_csr[e];
        float4 v = ((const float4*)HW)[(size_t)s * 32 + f4];
        acc.x += v.x * nv; acc.y += v.y * nv;
        acc.z += v.z * nv; acc.w += v.w * nv;
    }
    ((float4*)AGG)[(size_t)g * 32 + f4] = acc;
}

// layer 3: hw3[n] = dot(relu(h2[n,:]), W3);  agg3_init[n] = hw3[n]*dis^2 + b3
__global__ __launch_bounds__(256) void k_gemv(const float* __restrict__ H,
                                              const float* __restrict__ W3,
                                              const float* __restrict__ b3,
                                              const float* __restrict__ dis,
                                              float* __restrict__ hw3,
                                              float* __restrict__ agg3, int nN) {
    int wid = (blockIdx.x * 256 + threadIdx.x) >> 6;
    int lane = threadIdx.x & 63;
    if (wid >= nN) return;
    float v0 = fmaxf(H[(size_t)wid * 128 + lane], 0.f);
    float v1 = fmaxf(H[(size_t)wid * 128 + 64 + lane], 0.f);
    float sum = v0 * W3[lane] + v1 * W3[64 + lane];
#pragma unroll
    for (int off = 32; off > 0; off >>= 1) sum += __shfl_down(sum, off);
    if (lane == 0) {
        hw3[wid] = sum;
        float dn = dis[wid];
        agg3[wid] = sum * dn * dn + b3[0];
    }
}

// scalar pull-aggregation + final relu, fused into d_out
__global__ __launch_bounds__(256) void k_gather3(const float* __restrict__ hw3,
                                                 const int* __restrict__ row_ptr,
                                                 const int* __restrict__ src_csr,
                                                 const float* __restrict__ norm_csr,
                                                 float* __restrict__ out, int nN) {
    int i = blockIdx.x * 256 + threadIdx.x;
    if (i >= nN) return;
    float acc = out[i];  // agg3 init (self-loop + bias)
    int beg = row_ptr[i], end = row_ptr[i + 1];
    for (int e = beg; e < end; ++e) acc += hw3[src_csr[e]] * norm_csr[e];
    out[i] = fmaxf(acc, 0.f);
}

extern "C" void kernel_launch(void* const* d_in, const int* in_sizes, int n_in,
                              void* d_out, int out_size, void* d_ws, size_t ws_size,
                              hipStream_t stream) {
    const float* x  = (const float*)d_in[0];
    const int*   ei = (const int*)d_in[1];
    const float* W1 = (const float*)d_in[2];
    const float* b1 = (const float*)d_in[3];
    const float* W2 = (const float*)d_in[4];
    const float* b2 = (const float*)d_in[5];
    const float* W3 = (const float*)d_in[6];
    const float* b3 = (const float*)d_in[7];

    const int nN = in_sizes[0] / 128;
    const int nE = in_sizes[1] / 2;
    const int* src = ei;
    const int* dst = ei + nE;

    // workspace layout
    char* p = (char*)d_ws;
    int*   cnt      = (int*)p;            p += (size_t)nN * 4;        // counts -> cursor
    int*   row_ptr  = (int*)p;            p += (size_t)(nN + 1) * 4;
    int*   src_csr  = (int*)p;            p += (size_t)nE * 4;
    float* norm_csr = (float*)p;          p += (size_t)nE * 4;
    float* dis      = (float*)p;          p += (size_t)nN * 4;
    float* bufA     = (float*)p;          p += (size_t)nN * 128 * 4;  // hw (+ hw3 reuse)
    float* bufB     = (float*)p;          p += (size_t)nN * 128 * 4;  // h / agg
    float* hw3      = bufA;               // bufA free by the time gemv runs
    float* agg3     = (float*)d_out;

    const int BE  = (nE + 255) / 256;
    const int BN  = (nN + 255) / 256;
    const int BG  = (nN + 63) / 64;
    const int BGA = (nN + 7) / 8;
    const int BGV = (nN + 3) / 4;

    // --- CSR build + norm precompute ---
    hipMemsetAsync(cnt, 0, (size_t)nN * sizeof(int), stream);
    k_count<<<BE, 256, 0, stream>>>(dst, cnt, nE);
    k_rsqrt<<<BN, 256, 0, stream>>>(cnt, dis, nN);
    k_scan <<<1, 1024, 0, stream>>>(cnt, row_ptr, nN);
    k_bin  <<<BE, 256, 0, stream>>>(src, dst, dis, cnt, src_csr, norm_csr, nE);

    // --- layer 1: x -> bufB ---
    k_gemm128<<<BG, 256, 0, stream>>>(x, W1, dis, b1, bufA, bufB, nN, 0);
    k_gather <<<BGA, 256, 0, stream>>>(bufA, row_ptr, src_csr, norm_csr, bufB, nN);

    // --- layer 2: relu(bufB) -> bufB ---
    k_gemm128<<<BG, 256, 0, stream>>>(bufB, W2, dis, b2, bufA, bufB, nN, 1);
    k_gather <<<BGA, 256, 0, stream>>>(bufA, row_ptr, src_csr, norm_csr, bufB, nN);

    // --- layer 3: relu(bufB) -> d_out ---
    k_gemv   <<<BGV, 256, 0, stream>>>(bufB, W3, b3, dis, hw3, agg3, nN);
    k_gather3<<<BN, 256, 0, stream>>>(hw3, row_ptr, src_csr, norm_csr, agg3, nN);
}

// Round 3
// 402.203 us; speedup vs baseline: 5.6954x; 1.2016x over previous
//
#include <hip/hip_runtime.h>

// ---------------------------------------------------------------------------
// 3-layer GCN, CSR-gather formulation (no fp32 atomics in the hot path).
// Per call: build CSR by dst (count -> hierarchical scan -> bin), then/layer:
//   GEMM (writes hw + agg-init with self-loop & bias folded in)
//   gather: agg[n] += sum_{e in CSR[n]} hw[src_e] * norm_e   (register acc)
// ---------------------------------------------------------------------------

__global__ __launch_bounds__(256) void k_count(const int* __restrict__ dst,
                                               int* __restrict__ cnt, int nE) {
    int e = blockIdx.x * 256 + threadIdx.x;
    if (e < nE) atomicAdd(&cnt[dst[e]], 1);
}

__global__ __launch_bounds__(256) void k_rsqrt(const int* __restrict__ cnt,
                                               float* __restrict__ dis, int nN) {
    int i = blockIdx.x * 256 + threadIdx.x;
    if (i < nN) dis[i] = rsqrtf((float)cnt[i] + 1.0f);
}

// hierarchical scan, stage 1: per-block (256-wide) exclusive scan + block sum
__global__ __launch_bounds__(256) void k_scan_blk(const int* __restrict__ cnt,
                                                  int* __restrict__ excl,
                                                  int* __restrict__ blk_sum, int nN) {
    __shared__ int sm[256];
    const int t = threadIdx.x;
    int i = blockIdx.x * 256 + t;
    int v = (i < nN) ? cnt[i] : 0;
    sm[t] = v;
    __syncthreads();
#pragma unroll
    for (int off = 1; off < 256; off <<= 1) {
        int x = (t >= off) ? sm[t - off] : 0;
        __syncthreads();
        sm[t] += x;
        __syncthreads();
    }
    if (i < nN) excl[i] = sm[t] - v;
    if (t == 255) blk_sum[blockIdx.x] = sm[255];
}

// stage 2: single small block scans the block sums (nB <= 256)
__global__ __launch_bounds__(256) void k_scan_top(int* __restrict__ blk_sum, int nB) {
    __shared__ int sm[256];
    const int t = threadIdx.x;
    int v = (t < nB) ? blk_sum[t] : 0;
    sm[t] = v;
    __syncthreads();
#pragma unroll
    for (int off = 1; off < 256; off <<= 1) {
        int x = (t >= off) ? sm[t - off] : 0;
        __syncthreads();
        sm[t] += x;
        __syncthreads();
    }
    if (t < nB) blk_sum[t] = sm[t] - v;   // exclusive offsets in place
    if (t == 0) blk_sum[nB] = sm[255];    // grand total
}

// stage 3: add block offsets -> row_ptr + cursor copy
__global__ __launch_bounds__(256) void k_scan_add(const int* __restrict__ excl,
                                                  const int* __restrict__ blk_sum,
                                                  int* __restrict__ row_ptr,
                                                  int* __restrict__ cursor,
                                                  int nN, int nB) {
    int i = blockIdx.x * 256 + threadIdx.x;
    if (i < nN) {
        int v = excl[i] + blk_sum[i >> 8];
        row_ptr[i] = v;
        cursor[i] = v;
    }
    if (i == 0) row_ptr[nN] = blk_sum[nB];
}

__global__ __launch_bounds__(256) void k_bin(const int* __restrict__ src,
                                             const int* __restrict__ dst,
                                             const float* __restrict__ dis,
                                             int* __restrict__ cursor,
                                             int* __restrict__ src_csr,
                                             float* __restrict__ norm_csr, int nE) {
    int e = blockIdx.x * 256 + threadIdx.x;
    if (e >= nE) return;
    int s = src[e], d = dst[e];
    int pos = atomicAdd(&cursor[d], 1);
    src_csr[pos] = s;
    norm_csr[pos] = dis[s] * dis[d];
}

// Y = (relu?(X)) @ W   [nrows x 128] @ [128 x 128]
// HW  <- Y ;  AGG <- Y * dis[row]^2 + bias   (self-loop + bias folded in)
// X and AGG may alias: each block stages its own 64 rows to LDS before storing.
__global__ __launch_bounds__(256) void k_gemm128(const float* X,
                                                 const float* __restrict__ W,
                                                 const float* __restrict__ dis,
                                                 const float* __restrict__ bias,
                                                 float* __restrict__ HW,
                                                 float* AGG,
                                                 int nrows, int relu_in) {
    __shared__ float xs[64 * 128];
    __shared__ float wsm[32 * 128];
    const int t = threadIdx.x;
    const int row0 = blockIdx.x * 64;
    const int tr = t >> 5;
    const int tc = t & 31;

    float acc[8][4];
#pragma unroll
    for (int i = 0; i < 8; ++i)
#pragma unroll
        for (int c = 0; c < 4; ++c) acc[i][c] = 0.f;

#pragma unroll
    for (int i = 0; i < 8; ++i) {
        int f = t + i * 256;
        int r = f >> 5, k4 = f & 31;
        int gr = row0 + r;
        float4 v = make_float4(0.f, 0.f, 0.f, 0.f);
        if (gr < nrows) v = ((const float4*)X)[(size_t)gr * 32 + k4];
        if (relu_in) {
            v.x = fmaxf(v.x, 0.f); v.y = fmaxf(v.y, 0.f);
            v.z = fmaxf(v.z, 0.f); v.w = fmaxf(v.w, 0.f);
        }
        ((float4*)xs)[f] = v;
    }

    for (int kk = 0; kk < 128; kk += 32) {
#pragma unroll
        for (int i = 0; i < 4; ++i) {
            int f = t + i * 256;
            ((float4*)wsm)[f] = ((const float4*)W)[kk * 32 + f];
        }
        __syncthreads();
#pragma unroll
        for (int k4 = 0; k4 < 8; ++k4) {
            float4 b0 = *(const float4*)&wsm[(k4 * 4 + 0) * 128 + tc * 4];
            float4 b1 = *(const float4*)&wsm[(k4 * 4 + 1) * 128 + tc * 4];
            float4 b2 = *(const float4*)&wsm[(k4 * 4 + 2) * 128 + tc * 4];
            float4 b3 = *(const float4*)&wsm[(k4 * 4 + 3) * 128 + tc * 4];
#pragma unroll
            for (int i = 0; i < 8; ++i) {
                float4 a = *(const float4*)&xs[(tr * 8 + i) * 128 + kk + k4 * 4];
                acc[i][0] += a.x * b0.x + a.y * b1.x + a.z * b2.x + a.w * b3.x;
                acc[i][1] += a.x * b0.y + a.y * b1.y + a.z * b2.y + a.w * b3.y;
                acc[i][2] += a.x * b0.z + a.y * b1.z + a.z * b2.z + a.w * b3.z;
                acc[i][3] += a.x * b0.w + a.y * b1.w + a.z * b2.w + a.w * b3.w;
            }
        }
        __syncthreads();
    }

    const float4 bv = ((const float4*)bias)[tc];
#pragma unroll
    for (int i = 0; i < 8; ++i) {
        int gr = row0 + tr * 8 + i;
        if (gr < nrows) {
            float dn = dis[gr];
            float sn = dn * dn;
            float4 hv = make_float4(acc[i][0], acc[i][1], acc[i][2], acc[i][3]);
            ((float4*)HW)[(size_t)gr * 32 + tc] = hv;
            float4 av = make_float4(hv.x * sn + bv.x, hv.y * sn + bv.y,
                                    hv.z * sn + bv.z, hv.w * sn + bv.w);
            ((float4*)AGG)[(size_t)gr * 32 + tc] = av;
        }
    }
}

// pull-aggregation: 32 threads per node, float4 per thread, register acc,
// single write per output element. AGG pre-initialized with self-loop + bias.
__global__ __launch_bounds__(256) void k_gather(const float* __restrict__ HW,
                                                const int* __restrict__ row_ptr,
                                                const int* __restrict__ src_csr,
                                                const float* __restrict__ norm_csr,
                                                float* __restrict__ AGG, int nN) {
    int g = blockIdx.x * 8 + (threadIdx.x >> 5);
    if (g >= nN) return;
    int f4 = threadIdx.x & 31;
    int beg = row_ptr[g], end = row_ptr[g + 1];
    float4 acc = ((const float4*)AGG)[(size_t)g * 32 + f4];
    int e = beg;
    for (; e + 1 < end; e += 2) {  // 2-way unroll for load ILP
        int s0 = src_csr[e], s1 = src_csr[e + 1];
        float n0 = norm_csr[e], n1 = norm_csr[e + 1];
        float4 v0 = ((const float4*)HW)[(size_t)s0 * 32 + f4];
        float4 v1 = ((const float4*)HW)[(size_t)s1 * 32 + f4];
        acc.x += v0.x * n0 + v1.x * n1;
        acc.y += v0.y * n0 + v1.y * n1;
        acc.z += v0.z * n0 + v1.z * n1;
        acc.w += v0.w * n0 + v1.w * n1;
    }
    if (e < end) {
        int s = src_csr[e];
        float nv = norm_csr[e];
        float4 v = ((const float4*)HW)[(size_t)s * 32 + f4];
        acc.x += v.x * nv; acc.y += v.y * nv;
        acc.z += v.z * nv; acc.w += v.w * nv;
    }
    ((float4*)AGG)[(size_t)g * 32 + f4] = acc;
}

// layer 3: hw3[n] = dot(relu(h2[n,:]), W3);  agg3_init[n] = hw3[n]*dis^2 + b3
__global__ __launch_bounds__(256) void k_gemv(const float* __restrict__ H,
                                              const float* __restrict__ W3,
                                              const float* __restrict__ b3,
                                              const float* __restrict__ dis,
                                              float* __restrict__ hw3,
                                              float* __restrict__ agg3, int nN) {
    int wid = (blockIdx.x * 256 + threadIdx.x) >> 6;
    int lane = threadIdx.x & 63;
    if (wid >= nN) return;
    float v0 = fmaxf(H[(size_t)wid * 128 + lane], 0.f);
    float v1 = fmaxf(H[(size_t)wid * 128 + 64 + lane], 0.f);
    float sum = v0 * W3[lane] + v1 * W3[64 + lane];
#pragma unroll
    for (int off = 32; off > 0; off >>= 1) sum += __shfl_down(sum, off);
    if (lane == 0) {
        hw3[wid] = sum;
        float dn = dis[wid];
        agg3[wid] = sum * dn * dn + b3[0];
    }
}

// scalar pull-aggregation + final relu, fused into d_out
__global__ __launch_bounds__(256) void k_gather3(const float* __restrict__ hw3,
                                                 const int* __restrict__ row_ptr,
                                                 const int* __restrict__ src_csr,
                                                 const float* __restrict__ norm_csr,
                                                 float* __restrict__ out, int nN) {
    int i = blockIdx.x * 256 + threadIdx.x;
    if (i >= nN) return;
    float acc = out[i];  // agg3 init (self-loop + bias)
    int beg = row_ptr[i], end = row_ptr[i + 1];
    for (int e = beg; e < end; ++e) acc += hw3[src_csr[e]] * norm_csr[e];
    out[i] = fmaxf(acc, 0.f);
}

extern "C" void kernel_launch(void* const* d_in, const int* in_sizes, int n_in,
                              void* d_out, int out_size, void* d_ws, size_t ws_size,
                              hipStream_t stream) {
    const float* x  = (const float*)d_in[0];
    const int*   ei = (const int*)d_in[1];
    const float* W1 = (const float*)d_in[2];
    const float* b1 = (const float*)d_in[3];
    const float* W2 = (const float*)d_in[4];
    const float* b2 = (const float*)d_in[5];
    const float* W3 = (const float*)d_in[6];
    const float* b3 = (const float*)d_in[7];

    const int nN = in_sizes[0] / 128;
    const int nE = in_sizes[1] / 2;
    const int* src = ei;
    const int* dst = ei + nE;

    const int nB = (nN + 255) / 256;   // scan blocks

    // workspace layout
    char* p = (char*)d_ws;
    int*   cnt      = (int*)p;            p += (size_t)nN * 4;
    int*   cursor   = (int*)p;            p += (size_t)nN * 4;
    int*   excl     = (int*)p;            p += (size_t)nN * 4;
    int*   blk_sum  = (int*)p;            p += (size_t)(nB + 1) * 4;
    int*   row_ptr  = (int*)p;            p += (size_t)(nN + 1) * 4;
    int*   src_csr  = (int*)p;            p += (size_t)nE * 4;
    float* norm_csr = (float*)p;          p += (size_t)nE * 4;
    float* dis      = (float*)p;          p += (size_t)nN * 4;
    float* bufA     = (float*)p;          p += (size_t)nN * 128 * 4;  // hw
    float* bufB     = (float*)p;          p += (size_t)nN * 128 * 4;  // h / agg
    float* hw3      = bufA;               // bufA free by the time gemv runs
    float* agg3     = (float*)d_out;

    const int BE  = (nE + 255) / 256;
    const int BN  = (nN + 255) / 256;
    const int BG  = (nN + 63) / 64;
    const int BGA = (nN + 7) / 8;
    const int BGV = (nN + 3) / 4;

    // --- CSR build + norm precompute ---
    hipMemsetAsync(cnt, 0, (size_t)nN * sizeof(int), stream);
    k_count   <<<BE, 256, 0, stream>>>(dst, cnt, nE);
    k_rsqrt   <<<BN, 256, 0, stream>>>(cnt, dis, nN);
    k_scan_blk<<<nB, 256, 0, stream>>>(cnt, excl, blk_sum, nN);
    k_scan_top<<<1, 256, 0, stream>>>(blk_sum, nB);
    k_scan_add<<<nB, 256, 0, stream>>>(excl, blk_sum, row_ptr, cursor, nN, nB);
    k_bin     <<<BE, 256, 0, stream>>>(src, dst, dis, cursor, src_csr, norm_csr, nE);

    // --- layer 1: x -> bufB ---
    k_gemm128<<<BG, 256, 0, stream>>>(x, W1, dis, b1, bufA, bufB, nN, 0);
    k_gather <<<BGA, 256, 0, stream>>>(bufA, row_ptr, src_csr, norm_csr, bufB, nN);

    // --- layer 2: relu(bufB) -> bufB ---
    k_gemm128<<<BG, 256, 0, stream>>>(bufB, W2, dis, b2, bufA, bufB, nN, 1);
    k_gather <<<BGA, 256, 0, stream>>>(bufA, row_ptr, src_csr, norm_csr, bufB, nN);

    // --- layer 3: relu(bufB) -> d_out ---
    k_gemv   <<<BGV, 256, 0, stream>>>(bufB, W3, b3, dis, hw3, agg3, nN);
    k_gather3<<<BN, 256, 0, stream>>>(hw3, row_ptr, src_csr, norm_csr, agg3, nN);
}